// Round 13
// baseline (403.972 us; speedup 1.0000x reference)
//
#include <hip/hip_runtime.h>
#include <hip/hip_bf16.h>
#include <math.h>

// Problem dims
constexpr int NN  = 8192;
constexpr int EE  = 262144;
constexpr int IN  = 3000;
constexpr int INP = 3008;   // IN padded to mult of 64
constexpr int HID = 256;
constexpr int OUT = 64;

// Output offsets (floats) in d_out: (h2, h3, ret, ret_a, h2, h2_a)
constexpr long O_H2   = 0;
constexpr long O_H3   = 524288;          // 8192*64
constexpr long O_RET  = 25100288;        // + 8192*3000
constexpr long O_RETA = 25116672;        // + 8192*2
constexpr long O_H2B  = 25133056;        // + 8192*2
constexpr long O_H2A  = 25657344;        // + 8192*64

typedef __attribute__((ext_vector_type(8))) short short8v;   // 8 bf16 (4 VGPRs)
typedef __attribute__((ext_vector_type(4))) float f32x4;     // MFMA accumulator

__device__ __forceinline__ short f2bf(float f) {   // RNE f32 -> bf16 bits
    unsigned u = __float_as_uint(f);
    return (short)((u + 0x7FFF + ((u >> 16) & 1)) >> 16);
}
__device__ __forceinline__ float bf2f(unsigned short u) {
    return __uint_as_float(((unsigned)u) << 16);
}

// ================= conversion kernels (one-time per launch) ================================
__global__ void cvt_W1t(const float* __restrict__ W, unsigned short* __restrict__ Wt) {
    int i = blockIdx.x * 256 + threadIdx.x;            // over 256*3008
    int n = i / INP, k = i % INP;
    Wt[i] = (k < IN) ? (unsigned short)f2bf(W[(long)k * HID + n]) : 0;
}
__global__ void cvt_W2t(const float* __restrict__ W, unsigned short* __restrict__ Wt) {
    int i = blockIdx.x * 256 + threadIdx.x;            // over 64*256
    int n = i / HID, k = i % HID;
    Wt[i] = (unsigned short)f2bf(W[(long)k * OUT + n]);
}
__global__ void cvt_Wd1t(const float* __restrict__ W, unsigned short* __restrict__ Wt) {
    int i = blockIdx.x * 256 + threadIdx.x;            // over 256*64
    int n = i / OUT, k = i % OUT;
    Wt[i] = (unsigned short)f2bf(W[(long)k * HID + n]);
}
__global__ void cvt_Wd2t(const float* __restrict__ W, unsigned short* __restrict__ Wt) {
    int i = blockIdx.x * 256 + threadIdx.x;            // over 3072*256
    int n = i / HID, k = i % HID;
    Wt[i] = (n < IN) ? (unsigned short)f2bf(W[(long)k * IN + n]) : 0;
}

// ================= feat GEMM: [feat;feat_a][16384,3000] @ W1 -> partials ===================
// 128x128 tile, BK=64, reg-prefetch, f32 A converted during staging.
// Split-K=4: partials Cpart[z][16384][256] f32. grid dim3(2,128,4) = 1024 blocks = 4/CU.
__global__ __launch_bounds__(256) void feat_gemm(const float* __restrict__ A0,
                                                 const float* __restrict__ A1,
                                                 const unsigned short* __restrict__ Bt,
                                                 float* __restrict__ Cpart) {
    __shared__ unsigned short As[128][72];
    __shared__ unsigned short Bs[128][72];
    int xb = blockIdx.x, yb = blockIdx.y;
    int pass = yb >> 6;
    int row0 = (yb & 63) * 128, col0 = xb * 128;
    const float* A = pass ? A1 : A0;
    int t = threadIdx.x, w = t >> 6, l = t & 63;
    int sr = t >> 1, sh = (t & 1) * 32;
    int wm = (w >> 1) * 64, wn = (w & 1) * 64;
    int fr = l & 15, fq = l >> 4;
    const unsigned short* Bp = Bt + (long)(col0 + sr) * INP + sh;
    const float* Arow = A + (long)(row0 + sr) * IN;

    int tb = blockIdx.z * 12;
    int ktiles = min(12, 47 - tb);          // 12,12,12,11

    float4  paf[8];
    short8v pb[4];
    auto loadA = [&](int k0) {
        const float* Ar = Arow + k0 + sh;
        if (k0 + 64 <= IN) {
#pragma unroll
            for (int q = 0; q < 8; ++q) paf[q] = *reinterpret_cast<const float4*>(Ar + q * 4);
        } else {
#pragma unroll
            for (int q = 0; q < 8; ++q) {
                int kb = k0 + sh + q * 4;
                float4 v;
                v.x = (kb + 0 < IN) ? Ar[q * 4 + 0] : 0.f;
                v.y = (kb + 1 < IN) ? Ar[q * 4 + 1] : 0.f;
                v.z = (kb + 2 < IN) ? Ar[q * 4 + 2] : 0.f;
                v.w = (kb + 3 < IN) ? Ar[q * 4 + 3] : 0.f;
                paf[q] = v;
            }
        }
    };
    auto loadB = [&](int k0) {
#pragma unroll
        for (int q = 0; q < 4; ++q) pb[q] = *reinterpret_cast<const short8v*>(Bp + k0 + q * 8);
    };
    loadA(tb * 64); loadB(tb * 64);

    f32x4 acc[4][4] = {};
    for (int tt = 0; tt < ktiles; ++tt) {
#pragma unroll
        for (int q = 0; q < 4; ++q) {
            float4 v0 = paf[q * 2], v1 = paf[q * 2 + 1];
            short8v s;
            s[0]=f2bf(v0.x); s[1]=f2bf(v0.y); s[2]=f2bf(v0.z); s[3]=f2bf(v0.w);
            s[4]=f2bf(v1.x); s[5]=f2bf(v1.y); s[6]=f2bf(v1.z); s[7]=f2bf(v1.w);
            *reinterpret_cast<short8v*>(&As[sr][sh + q * 8]) = s;
        }
#pragma unroll
        for (int q = 0; q < 4; ++q)
            *reinterpret_cast<short8v*>(&Bs[sr][sh + q * 8]) = pb[q];
        __syncthreads();
        if (tt + 1 < ktiles) {
            int k0 = (tb + tt + 1) * 64;
            loadA(k0); loadB(k0);
        }
#pragma unroll
        for (int kk = 0; kk < 2; ++kk) {
            short8v fa[4], fb[4];
#pragma unroll
            for (int i = 0; i < 4; ++i)
                fa[i] = *reinterpret_cast<const short8v*>(&As[wm + i * 16 + fr][kk * 32 + fq * 8]);
#pragma unroll
            for (int j = 0; j < 4; ++j)
                fb[j] = *reinterpret_cast<const short8v*>(&Bs[wn + j * 16 + fr][kk * 32 + fq * 8]);
#pragma unroll
            for (int i = 0; i < 4; ++i)
#pragma unroll
                for (int j = 0; j < 4; ++j)
                    acc[i][j] = __builtin_amdgcn_mfma_f32_16x16x32_bf16(fa[i], fb[j], acc[i][j], 0, 0, 0);
        }
        __syncthreads();
    }
    int dc = l & 15;
    long zbase = (long)blockIdx.z * 16384 * 256;
    long rbase = (long)(pass * NN + row0) * 256;
#pragma unroll
    for (int i = 0; i < 4; ++i)
#pragma unroll
        for (int j = 0; j < 4; ++j) {
            int c = col0 + wn + j * 16 + dc;
#pragma unroll
            for (int q = 0; q < 4; ++q) {
                int r = wm + i * 16 + fq * 4 + q;
                Cpart[zbase + rbase + (long)r * 256 + c] = acc[i][j][q];
            }
        }
}

// ---- fused: sum 4 split-K partials -> h_bf2 (bf16) + attention coefficients --------------
// grid 4096 x 256 (4 waves, wave = one row of 16384). lane handles 4 channels.
__global__ __launch_bounds__(256) void reduce_attn(const float* __restrict__ p,
                                                   const float* __restrict__ att_src,
                                                   const float* __restrict__ att_dst,
                                                   unsigned short* __restrict__ hb,
                                                   float* __restrict__ a_src,
                                                   float* __restrict__ a_dst) {
    int wave = threadIdx.x >> 6, lane = threadIdx.x & 63;
    int n = blockIdx.x * 4 + wave;          // 0..16383
    long base = (long)n * 256 + lane * 4;
    float4 a = *reinterpret_cast<const float4*>(p + base);
    float4 b = *reinterpret_cast<const float4*>(p + 4194304 + base);
    float4 c = *reinterpret_cast<const float4*>(p + 8388608 + base);
    float4 d = *reinterpret_cast<const float4*>(p + 12582912 + base);
    float4 hv;
    hv.x = a.x + b.x + c.x + d.x;
    hv.y = a.y + b.y + c.y + d.y;
    hv.z = a.z + b.z + c.z + d.z;
    hv.w = a.w + b.w + c.w + d.w;
    ushort4 r;
    r.x = (unsigned short)f2bf(hv.x);
    r.y = (unsigned short)f2bf(hv.y);
    r.z = (unsigned short)f2bf(hv.z);
    r.w = (unsigned short)f2bf(hv.w);
    *reinterpret_cast<ushort4*>(hb + base) = r;
    float4 vs = *reinterpret_cast<const float4*>(&att_src[lane * 4]);
    float4 vd = *reinterpret_cast<const float4*>(&att_dst[lane * 4]);
    float s1 = hv.x * vs.x + hv.y * vs.y + hv.z * vs.z + hv.w * vs.w;
    float s2 = hv.x * vd.x + hv.y * vd.y + hv.z * vd.z + hv.w * vd.w;
#pragma unroll
    for (int off = 32; off > 0; off >>= 1) {
        s1 += __shfl_down(s1, off);
        s2 += __shfl_down(s2, off);
    }
    if (lane == 0) { a_src[n] = s1; a_dst[n] = s2; }
}

// ================= W2 GEMM with mega-epilogue ==============================================
__global__ __launch_bounds__(256) void w2_gemm(const unsigned short* __restrict__ A,
                                               const unsigned short* __restrict__ Bt,
                                               float* __restrict__ h2f,
                                               unsigned short* __restrict__ h2b,
                                               unsigned short* __restrict__ HT,
                                               float* __restrict__ out) {
    __shared__ unsigned short As[64][72];
    __shared__ unsigned short Bs[64][72];
    int t = threadIdx.x, w = t >> 6, l = t & 63;
    int row0 = blockIdx.y * 64;
    int srow = t >> 2, scol = (t & 3) * 16;
    const unsigned short* Ap = A + (long)(row0 + srow) * HID + scol;
    const unsigned short* Bp = Bt + (long)srow * HID + scol;   // 64 rows only
    int wm = (w >> 1) * 32, wn = (w & 1) * 32;
    int fr = l & 15, fq = l >> 4;

    short8v a0r, a1r, b0r, b1r;
    a0r = *reinterpret_cast<const short8v*>(Ap);
    a1r = *reinterpret_cast<const short8v*>(Ap + 8);
    b0r = *reinterpret_cast<const short8v*>(Bp);
    b1r = *reinterpret_cast<const short8v*>(Bp + 8);

    f32x4 acc[2][2] = {};
    for (int tt = 0; tt < 4; ++tt) {
        *reinterpret_cast<short8v*>(&As[srow][scol])     = a0r;
        *reinterpret_cast<short8v*>(&As[srow][scol + 8]) = a1r;
        *reinterpret_cast<short8v*>(&Bs[srow][scol])     = b0r;
        *reinterpret_cast<short8v*>(&Bs[srow][scol + 8]) = b1r;
        __syncthreads();
        if (tt + 1 < 4) {
            const unsigned short* Ap2 = Ap + (tt + 1) * 64;
            const unsigned short* Bp2 = Bp + (tt + 1) * 64;
            a0r = *reinterpret_cast<const short8v*>(Ap2);
            a1r = *reinterpret_cast<const short8v*>(Ap2 + 8);
            b0r = *reinterpret_cast<const short8v*>(Bp2);
            b1r = *reinterpret_cast<const short8v*>(Bp2 + 8);
        }
#pragma unroll
        for (int kk = 0; kk < 2; ++kk) {
            short8v fa0 = *reinterpret_cast<const short8v*>(&As[wm + fr][kk * 32 + fq * 8]);
            short8v fa1 = *reinterpret_cast<const short8v*>(&As[wm + 16 + fr][kk * 32 + fq * 8]);
            short8v fb0 = *reinterpret_cast<const short8v*>(&Bs[wn + fr][kk * 32 + fq * 8]);
            short8v fb1 = *reinterpret_cast<const short8v*>(&Bs[wn + 16 + fr][kk * 32 + fq * 8]);
            acc[0][0] = __builtin_amdgcn_mfma_f32_16x16x32_bf16(fa0, fb0, acc[0][0], 0, 0, 0);
            acc[0][1] = __builtin_amdgcn_mfma_f32_16x16x32_bf16(fa0, fb1, acc[0][1], 0, 0, 0);
            acc[1][0] = __builtin_amdgcn_mfma_f32_16x16x32_bf16(fa1, fb0, acc[1][0], 0, 0, 0);
            acc[1][1] = __builtin_amdgcn_mfma_f32_16x16x32_bf16(fa1, fb1, acc[1][1], 0, 0, 0);
        }
        __syncthreads();
    }
    int dc = l & 15;
    int pass = row0 >> 13;
#pragma unroll
    for (int i = 0; i < 2; ++i)
#pragma unroll
        for (int j = 0; j < 2; ++j) {
            int c = wn + j * 16 + dc;
#pragma unroll
            for (int q = 0; q < 4; ++q) {
                int r = row0 + wm + i * 16 + fq * 4 + q;
                int n = r & 8191;
                float v = acc[i][j][q];
                unsigned short vb = (unsigned short)f2bf(v);
                h2f[(long)pass * 524288 + (long)n * 64 + c] = v;
                if (pass == 0) {
                    out[O_H2  + (long)n * 64 + c] = v;
                    out[O_H2B + (long)n * 64 + c] = v;
                    h2b[(long)n * 64 + c] = vb;
                } else {
                    out[O_H2A + (long)n * 64 + c] = v;
                }
                HT[(long)(pass * 64 + c) * NN + n] = vb;
            }
        }
}

// ================= 128x128 bf16 GEMM (Wd2) ================================================
__global__ __launch_bounds__(256) void wd2_gemm(const unsigned short* __restrict__ A,
                                                const unsigned short* __restrict__ Bt,
                                                const float* __restrict__ bias,
                                                float* __restrict__ Cf) {
    __shared__ unsigned short As[128][72];
    __shared__ unsigned short Bs[128][72];
    int t = threadIdx.x, w = t >> 6, l = t & 63;
    int row0 = blockIdx.y * 128, col0 = blockIdx.x * 128;
    int sr = t >> 1, sh = (t & 1) * 32;
    int wm = (w >> 1) * 64, wn = (w & 1) * 64;
    int fr = l & 15, fq = l >> 4;
    const unsigned short* Ap = A  + (long)(row0 + sr) * HID + sh;
    const unsigned short* Bp = Bt + (long)(col0 + sr) * HID + sh;

    short8v pa[4], pb[4];
#pragma unroll
    for (int q = 0; q < 4; ++q) pa[q] = *reinterpret_cast<const short8v*>(Ap + q * 8);
#pragma unroll
    for (int q = 0; q < 4; ++q) pb[q] = *reinterpret_cast<const short8v*>(Bp + q * 8);

    f32x4 acc[4][4] = {};
    for (int tt = 0; tt < 4; ++tt) {
#pragma unroll
        for (int q = 0; q < 4; ++q) {
            *reinterpret_cast<short8v*>(&As[sr][sh + q * 8]) = pa[q];
            *reinterpret_cast<short8v*>(&Bs[sr][sh + q * 8]) = pb[q];
        }
        __syncthreads();
        if (tt + 1 < 4) {
            int k0 = (tt + 1) * 64;
#pragma unroll
            for (int q = 0; q < 4; ++q) pa[q] = *reinterpret_cast<const short8v*>(Ap + k0 + q * 8);
#pragma unroll
            for (int q = 0; q < 4; ++q) pb[q] = *reinterpret_cast<const short8v*>(Bp + k0 + q * 8);
        }
#pragma unroll
        for (int kk = 0; kk < 2; ++kk) {
            short8v fa[4], fb[4];
#pragma unroll
            for (int i = 0; i < 4; ++i)
                fa[i] = *reinterpret_cast<const short8v*>(&As[wm + i * 16 + fr][kk * 32 + fq * 8]);
#pragma unroll
            for (int j = 0; j < 4; ++j)
                fb[j] = *reinterpret_cast<const short8v*>(&Bs[wn + j * 16 + fr][kk * 32 + fq * 8]);
#pragma unroll
            for (int i = 0; i < 4; ++i)
#pragma unroll
                for (int j = 0; j < 4; ++j)
                    acc[i][j] = __builtin_amdgcn_mfma_f32_16x16x32_bf16(fa[i], fb[j], acc[i][j], 0, 0, 0);
        }
        __syncthreads();
    }
    int dc = l & 15;
#pragma unroll
    for (int i = 0; i < 4; ++i)
#pragma unroll
        for (int j = 0; j < 4; ++j) {
            int c = col0 + wn + j * 16 + dc;
            if (c < IN) {
                float bb = bias[c];
#pragma unroll
                for (int q = 0; q < 4; ++q) {
                    int r = row0 + wm + i * 16 + fq * 4 + q;
                    Cf[(long)r * IN + c] = acc[i][j][q] + bb;
                }
            }
        }
}

// ================= 64x64 bf16 GEMM (Wd1) ===================================================
__global__ __launch_bounds__(256) void wd1_gemm(const unsigned short* __restrict__ A,
                                                const unsigned short* __restrict__ Bt,
                                                const float* __restrict__ bias,
                                                float* __restrict__ C) {
    __shared__ unsigned short As[64][72];
    __shared__ unsigned short Bs[64][72];
    int t = threadIdx.x, w = t >> 6, l = t & 63;
    int row0 = blockIdx.y * 64, col0 = blockIdx.x * 64;
    int srow = t >> 2, scol = (t & 3) * 16;
    const unsigned short* Ap = A  + (long)(row0 + srow) * OUT + scol;   // K=64
    const unsigned short* Bp = Bt + (long)(col0 + srow) * OUT + scol;
    int wm = (w >> 1) * 32, wn = (w & 1) * 32;
    int fr = l & 15, fq = l >> 4;

    *reinterpret_cast<short8v*>(&As[srow][scol])     = *reinterpret_cast<const short8v*>(Ap);
    *reinterpret_cast<short8v*>(&As[srow][scol + 8]) = *reinterpret_cast<const short8v*>(Ap + 8);
    *reinterpret_cast<short8v*>(&Bs[srow][scol])     = *reinterpret_cast<const short8v*>(Bp);
    *reinterpret_cast<short8v*>(&Bs[srow][scol + 8]) = *reinterpret_cast<const short8v*>(Bp + 8);
    __syncthreads();
    f32x4 acc[2][2] = {};
#pragma unroll
    for (int kk = 0; kk < 2; ++kk) {
        short8v fa0 = *reinterpret_cast<const short8v*>(&As[wm + fr][kk * 32 + fq * 8]);
        short8v fa1 = *reinterpret_cast<const short8v*>(&As[wm + 16 + fr][kk * 32 + fq * 8]);
        short8v fb0 = *reinterpret_cast<const short8v*>(&Bs[wn + fr][kk * 32 + fq * 8]);
        short8v fb1 = *reinterpret_cast<const short8v*>(&Bs[wn + 16 + fr][kk * 32 + fq * 8]);
        acc[0][0] = __builtin_amdgcn_mfma_f32_16x16x32_bf16(fa0, fb0, acc[0][0], 0, 0, 0);
        acc[0][1] = __builtin_amdgcn_mfma_f32_16x16x32_bf16(fa0, fb1, acc[0][1], 0, 0, 0);
        acc[1][0] = __builtin_amdgcn_mfma_f32_16x16x32_bf16(fa1, fb0, acc[1][0], 0, 0, 0);
        acc[1][1] = __builtin_amdgcn_mfma_f32_16x16x32_bf16(fa1, fb1, acc[1][1], 0, 0, 0);
    }
    int dc = l & 15;
#pragma unroll
    for (int i = 0; i < 2; ++i)
#pragma unroll
        for (int j = 0; j < 2; ++j) {
            int c = col0 + wn + j * 16 + dc;
            float bb = bias[c];
#pragma unroll
            for (int q = 0; q < 4; ++q) {
                int r = row0 + wm + i * 16 + fq * 4 + q;
                C[(long)r * HID + c] = acc[i][j][q] + bb;
            }
        }
}

// ---------------- readout MFMA: split-K=8, bf16 partials -----------------------------------
// vsum = gneigh @ HT^T. BM=64, BN=128, BK=64, kchunk=1024. grid (128, 8) = 1024 blocks.
__global__ __launch_bounds__(256) void readout_mfma2(const float* __restrict__ gn,
                                                     const unsigned short* __restrict__ HT,
                                                     unsigned short* __restrict__ vsum_part,
                                                     float* __restrict__ rowsum_part) {
    __shared__ unsigned short As[64][72];
    __shared__ unsigned short Bs[128][72];
    __shared__ float rsacc[64][4];
    int t = threadIdx.x, w = t >> 6, l = t & 63;
    int row0 = blockIdx.x * 64;
    int kc = blockIdx.y, kbeg = kc * 1024;
    int asr = t >> 2, asc = (t & 3) * 16;
    int bsr = t >> 1, bsc = (t & 1) * 32;
    const float*          Ap = gn + (long)(row0 + asr) * NN + kbeg + asc;
    const unsigned short* Bp = HT + (long)bsr * NN + kbeg + bsc;
    int wm = (w >> 1) * 32, wn = (w & 1) * 64;
    int fr = l & 15, fq = l >> 4;

    float4  a4[4];
    short8v b8[4];
#pragma unroll
    for (int q = 0; q < 4; ++q) a4[q] = *reinterpret_cast<const float4*>(Ap + q * 4);
#pragma unroll
    for (int q = 0; q < 4; ++q) b8[q] = *reinterpret_cast<const short8v*>(Bp + q * 8);

    f32x4 acc[2][4] = {};
    float myrs = 0.f;
    for (int it = 0; it < 16; ++it) {
#pragma unroll
        for (int q = 0; q < 4; ++q) {
            float4 v = a4[q];
            ushort4 s;
            s.x = (unsigned short)f2bf(v.x);
            s.y = (unsigned short)f2bf(v.y);
            s.z = (unsigned short)f2bf(v.z);
            s.w = (unsigned short)f2bf(v.w);
            *reinterpret_cast<ushort4*>(&As[asr][asc + q * 4]) = s;
            myrs += v.x + v.y + v.z + v.w;
        }
#pragma unroll
        for (int q = 0; q < 4; ++q)
            *reinterpret_cast<short8v*>(&Bs[bsr][bsc + q * 8]) = b8[q];
        __syncthreads();
        if (it + 1 < 16) {
            const float*          Ap2 = Ap + (it + 1) * 64;
            const unsigned short* Bp2 = Bp + (it + 1) * 64;
#pragma unroll
            for (int q = 0; q < 4; ++q) a4[q] = *reinterpret_cast<const float4*>(Ap2 + q * 4);
#pragma unroll
            for (int q = 0; q < 4; ++q) b8[q] = *reinterpret_cast<const short8v*>(Bp2 + q * 8);
        }
#pragma unroll
        for (int kk = 0; kk < 2; ++kk) {
            short8v fa0 = *reinterpret_cast<const short8v*>(&As[wm + fr][kk * 32 + fq * 8]);
            short8v fa1 = *reinterpret_cast<const short8v*>(&As[wm + 16 + fr][kk * 32 + fq * 8]);
#pragma unroll
            for (int j = 0; j < 4; ++j) {
                short8v fb = *reinterpret_cast<const short8v*>(&Bs[wn + j * 16 + fr][kk * 32 + fq * 8]);
                acc[0][j] = __builtin_amdgcn_mfma_f32_16x16x32_bf16(fa0, fb, acc[0][j], 0, 0, 0);
                acc[1][j] = __builtin_amdgcn_mfma_f32_16x16x32_bf16(fa1, fb, acc[1][j], 0, 0, 0);
            }
        }
        __syncthreads();
    }
    rsacc[asr][t & 3] = myrs;
    __syncthreads();
    if (t < 64)
        rowsum_part[(long)kc * NN + row0 + t] =
            rsacc[t][0] + rsacc[t][1] + rsacc[t][2] + rsacc[t][3];
    int dc = l & 15;
#pragma unroll
    for (int i = 0; i < 2; ++i)
#pragma unroll
        for (int j = 0; j < 4; ++j) {
            int c = wn + j * 16 + dc;
#pragma unroll
            for (int q = 0; q < 4; ++q) {
                int r = row0 + wm + i * 16 + fq * 4 + q;
                vsum_part[((long)kc * NN + r) * 128 + c] = (unsigned short)f2bf(acc[i][j][q]);
            }
        }
}

// ---------------- CSR build ----------------------------------------------------------------
__global__ void deg_count(const int* __restrict__ dst, int* __restrict__ deg) {
    int i = blockIdx.x * 256 + threadIdx.x;
    if (i < EE) atomicAdd(&deg[dst[i]], 1);
}

__global__ __launch_bounds__(256) void scan_offsets(const int* __restrict__ deg,
                                                    int* __restrict__ off,
                                                    int* __restrict__ cursor) {
    __shared__ int part[256];
    int t = threadIdx.x;
    int base = t * 32;
    int local[32];
    int s = 0;
#pragma unroll
    for (int i = 0; i < 32; ++i) { local[i] = s; s += deg[base + i]; }
    part[t] = s;
    __syncthreads();
    for (int o2 = 1; o2 < 256; o2 <<= 1) {
        int v = (t >= o2) ? part[t - o2] : 0;
        __syncthreads();
        part[t] += v;
        __syncthreads();
    }
    int pre = (t == 0) ? 0 : part[t - 1];
#pragma unroll
    for (int i = 0; i < 32; ++i) {
        int v = pre + local[i];
        off[base + i] = v;
        cursor[base + i] = v;
    }
}

__global__ void scatter_edges(const int* __restrict__ src, const int* __restrict__ dst,
                              int* __restrict__ cursor, int* __restrict__ ssrc) {
    int i = blockIdx.x * 256 + threadIdx.x;
    if (i >= EE) return;
    int slot = atomicAdd(&cursor[dst[i]], 1);
    ssrc[slot] = src[i];
}

// ---------------- fused GAT gather (batched both passes) -----------------------------------
__global__ __launch_bounds__(256) void gat_gather(const int* __restrict__ ssrc,
                                                  const int* __restrict__ off,
                                                  const int* __restrict__ deg,
                                                  const float* __restrict__ asrc2,
                                                  const float* __restrict__ adst2,
                                                  const unsigned short* __restrict__ hb2,
                                                  unsigned short* __restrict__ gat2) {
    int wv = threadIdx.x >> 6, lane = threadIdx.x & 63;
    int d = blockIdx.x * 4 + wv;        // 0..16383
    int pass = d >> 13, node = d & 8191;
    const float* asrc = asrc2 + pass * NN;
    const unsigned short* h = hb2 + (long)pass * NN * HID;
    int o = off[node], n = deg[node];
    float ad = adst2[d];

    float m = -INFINITY;
    for (int j = lane; j < n; j += 64) {
        float e = asrc[ssrc[o + j]] + ad;
        e = e > 0.f ? e : 0.2f * e;
        m = fmaxf(m, e);
    }
#pragma unroll
    for (int t = 32; t; t >>= 1) m = fmaxf(m, __shfl_xor(m, t));
    float z = 0.f;
    for (int j = lane; j < n; j += 64) {
        float e = asrc[ssrc[o + j]] + ad;
        e = e > 0.f ? e : 0.2f * e;
        z += expf(e - m);
    }
#pragma unroll
    for (int t = 32; t; t >>= 1) z += __shfl_xor(z, t);
    float zinv = 1.0f / (z + 1e-16f);

    float4 acc = {0.f, 0.f, 0.f, 0.f};
    int j = 0;
    for (; j + 2 <= n; j += 2) {
        int s0 = ssrc[o + j], s1 = ssrc[o + j + 1];
        const ushort4 h0 = *reinterpret_cast<const ushort4*>(&h[(long)s0 * HID + lane * 4]);
        const ushort4 h1 = *reinterpret_cast<const ushort4*>(&h[(long)s1 * HID + lane * 4]);
        float e0 = asrc[s0] + ad; e0 = e0 > 0.f ? e0 : 0.2f * e0;
        float e1 = asrc[s1] + ad; e1 = e1 > 0.f ? e1 : 0.2f * e1;
        float a0 = expf(e0 - m) * zinv;
        float a1 = expf(e1 - m) * zinv;
        acc.x += a0 * bf2f(h0.x) + a1 * bf2f(h1.x);
        acc.y += a0 * bf2f(h0.y) + a1 * bf2f(h1.y);
        acc.z += a0 * bf2f(h0.z) + a1 * bf2f(h1.z);
        acc.w += a0 * bf2f(h0.w) + a1 * bf2f(h1.w);
    }
    if (j < n) {
        int s0 = ssrc[o + j];
        const ushort4 h0 = *reinterpret_cast<const ushort4*>(&h[(long)s0 * HID + lane * 4]);
        float e0 = asrc[s0] + ad; e0 = e0 > 0.f ? e0 : 0.2f * e0;
        float a0 = expf(e0 - m) * zinv;
        acc.x += a0 * bf2f(h0.x); acc.y += a0 * bf2f(h0.y);
        acc.z += a0 * bf2f(h0.z); acc.w += a0 * bf2f(h0.w);
    }
    ushort4 r;
    r.x = (unsigned short)f2bf(acc.x > 0.f ? acc.x : expm1f(acc.x));
    r.y = (unsigned short)f2bf(acc.y > 0.f ? acc.y : expm1f(acc.y));
    r.z = (unsigned short)f2bf(acc.z > 0.f ? acc.z : expm1f(acc.z));
    r.w = (unsigned short)f2bf(acc.w > 0.f ? acc.w : expm1f(acc.w));
    *reinterpret_cast<ushort4*>(&gat2[(long)d * HID + lane * 4]) = r;
}

// ---------------- batchnorm ----------------------------------------------------------------
__global__ void bn_partial(const float* __restrict__ zd, float* __restrict__ s,
                           float* __restrict__ sq) {
    int t = threadIdx.x;
    float a = 0.f, b = 0.f;
    int r0 = blockIdx.x * 128;
    for (int r = r0; r < r0 + 128; ++r) {
        float v = zd[(long)r * HID + t];
        a += v;
        b += v * v;
    }
    atomicAdd(&s[t], a);
    atomicAdd(&sq[t], b);
}

__global__ void bn_finalize(const float* __restrict__ s, const float* __restrict__ sq,
                            const float* __restrict__ gamma, const float* __restrict__ beta,
                            float* __restrict__ scale, float* __restrict__ shift) {
    int t = threadIdx.x;
    float mean = s[t] / (float)NN;
    float var  = sq[t] / (float)NN - mean * mean;
    float sc   = gamma[t] * rsqrtf(var + 1e-5f);
    scale[t] = sc;
    shift[t] = beta[t] - mean * sc;
}

__global__ void bn_apply_elu_bf(const float* __restrict__ zd, const float* __restrict__ scale,
                                const float* __restrict__ shift, unsigned short* __restrict__ zb) {
    for (long i = (long)blockIdx.x * blockDim.x + threadIdx.x; i < (long)NN * HID;
         i += (long)gridDim.x * blockDim.x) {
        int c = (int)(i & 255);
        float v = zd[i] * scale[c] + shift[c];
        v = v > 0.f ? v : expm1f(v);
        zb[i] = (unsigned short)f2bf(v);
    }
}

// ---------------- fused readout-norm + discriminator ---------------------------------------
// block = node r, 128 threads. vsum_part bf16 8x[8192][128], rowsum_part f32 8x[8192].
__global__ void readout_disc(const unsigned short* __restrict__ vsum_part,
                             const float* __restrict__ rowsum_part,
                             const float* __restrict__ h2f,
                             const float* __restrict__ W, const float* __restrict__ b,
                             float* __restrict__ ret, float* __restrict__ reta) {
    __shared__ float gg[128];
    int r = blockIdx.x, t = threadIdx.x;
    float rs = 0.f, v = 0.f;
#pragma unroll
    for (int kc = 0; kc < 8; ++kc) {
        rs += rowsum_part[(long)kc * NN + r];
        v  += bf2f(vsum_part[((long)kc * NN + r) * 128 + t]);
    }
    v /= rs;
    int w = t >> 6, lane = t & 63;
    float sq = v * v;
#pragma unroll
    for (int off = 32; off > 0; off >>= 1) sq += __shfl_xor(sq, off);
    float nrm = fmaxf(sqrtf(sq), 1e-12f);
    gg[t] = 1.0f / (1.0f + expf(-(v / nrm)));
    __syncthreads();
    const float* hp_base = h2f + (w ? 524288 : 0);
    const float* hm_base = h2f + (w ? 0 : 524288);
    float u = 0.f;
#pragma unroll 8
    for (int e = 0; e < 64; ++e) u += W[lane * 64 + e] * gg[w * 64 + e];
    float hp = hp_base[(long)r * 64 + lane];
    float hm = hm_base[(long)r * 64 + lane];
    float t1 = hp * u, t2 = hm * u;
#pragma unroll
    for (int off = 32; off > 0; off >>= 1) {
        t1 += __shfl_xor(t1, off);
        t2 += __shfl_xor(t2, off);
    }
    if (lane == 0) {
        float bb = b[0];
        float* dstp = w ? reta : ret;
        dstp[r * 2]     = t1 + bb;
        dstp[r * 2 + 1] = t2 + bb;
    }
}

// ---------------- driver -------------------------------------------------------------------
extern "C" void kernel_launch(void* const* d_in, const int* in_sizes, int n_in,
                              void* d_out, int out_size, void* d_ws, size_t ws_size,
                              hipStream_t stream) {
    const float* feat    = (const float*)d_in[0];
    const float* feat_a  = (const float*)d_in[1];
    const float* gneigh  = (const float*)d_in[2];
    const float* W1      = (const float*)d_in[3];
    const float* att_src = (const float*)d_in[4];
    const float* att_dst = (const float*)d_in[5];
    const float* W2      = (const float*)d_in[6];
    const float* Wd1     = (const float*)d_in[7];
    const float* bd1     = (const float*)d_in[8];
    const float* gamma   = (const float*)d_in[9];
    const float* beta    = (const float*)d_in[10];
    const float* Wd2     = (const float*)d_in[11];
    const float* bd2     = (const float*)d_in[12];
    const float* disc_W  = (const float*)d_in[13];
    const float* disc_b  = (const float*)d_in[14];
    const int*   eidx    = (const int*)d_in[15];
    const int*   src = eidx;
    const int*   dst = eidx + EE;
    float* out = (float*)d_out;

    // workspace layout (floats)
    float* w = (float*)d_ws;
    unsigned short* h_bf2  = (unsigned short*)w;                   // [2][8192][256] bf16 = 2097152 f
    unsigned short* gat_bf2 = (unsigned short*)(w + 2097152);      // [2][8192][256] bf16 = 2097152 f
    float* zdec    = w + 4194304;                                  // [8192][256] f32 = 2097152 f
    unsigned short* zdec_bf = (unsigned short*)(zdec + 2097152);   // 1048576 f
    float* h2f     = zdec + 2097152 + 1048576;                     // [2][8192][64] = 1048576 f
    unsigned short* h2b = (unsigned short*)(h2f + 1048576);        // [8192][64] bf16 = 262144 f
    unsigned short* HT  = h2b + 524288;                            // [128][8192] bf16 = 524288 f
    float* asrc2   = (float*)(HT + 1048576);                       // 16384
    float* adst2   = asrc2 + 16384;                                // 16384
    float* bnsum   = adst2 + 16384;           // 256
    float* bnsq    = bnsum + 256;             // 256
    float* scale   = bnsq + 256;              // 256
    float* shift   = scale + 256;             // 256
    unsigned short* W1t  = (unsigned short*)(shift + 256);         // 770048 sh
    unsigned short* W2t  = W1t + 770048;                           // 16384 sh
    unsigned short* Wd1t = W2t + 16384;                            // 16384 sh
    unsigned short* Wd2t = Wd1t + 16384;                           // 786432 sh
    int*   ideg    = (int*)(Wd2t + 786432);   // 8192
    int*   ioff    = ideg + 8192;             // 8192
    int*   icur    = ioff + 8192;             // 8192
    int*   issrc   = icur + 8192;             // 262144
    // feat split-K partials: 4 x [16384][256] f32 = 64 MB in the not-yet-written h3 region
    float* part = out + O_H3;                 // 16777216 f <= 24576000 f available
    // readout-phase reuse: vsum bf16 8x[8192][128] = 16MB in h_bf2+gat_bf2 (dead);
    // rowsum f32 8x[8192] in zdec (dead after bn_apply)
    unsigned short* vsum_part = (unsigned short*)w;                // 8388608 sh = 4194304 f
    float* rowsum_part = zdec;                // 65536 f

    // ---- one-time weight conversions
    cvt_W1t<<<3008, 256, 0, stream>>>(W1, W1t);
    cvt_W2t<<<64, 256, 0, stream>>>(W2, W2t);
    cvt_Wd1t<<<64, 256, 0, stream>>>(Wd1, Wd1t);
    cvt_Wd2t<<<3072, 256, 0, stream>>>(Wd2, Wd2t);

    // ---- CSR build
    hipMemsetAsync(ideg, 0, 8192 * 4, stream);
    deg_count<<<EE / 256, 256, 0, stream>>>(dst, ideg);
    scan_offsets<<<1, 256, 0, stream>>>(ideg, ioff, icur);
    scatter_edges<<<EE / 256, 256, 0, stream>>>(src, dst, icur, issrc);

    // ---- encoder (both passes batched; split-K=4 for occupancy)
    feat_gemm<<<dim3(2, 128, 4), 256, 0, stream>>>(feat, feat_a, W1t, part);
    reduce_attn<<<4096, 256, 0, stream>>>(part, att_src, att_dst, h_bf2, asrc2, adst2);
    gat_gather<<<4096, 256, 0, stream>>>(issrc, ioff, ideg, asrc2, adst2, h_bf2, gat_bf2);
    w2_gemm<<<dim3(1, 256), 256, 0, stream>>>(gat_bf2, W2t, h2f, h2b, HT, out);

    // ---- decoder: h3 = elu(BN(h2 @ Wd1 + bd1)) @ Wd2 + bd2
    wd1_gemm<<<dim3(4, 128), 256, 0, stream>>>(h2b, Wd1t, bd1, zdec);
    hipMemsetAsync(bnsum, 0, 512 * 4, stream);
    bn_partial<<<64, 256, 0, stream>>>(zdec, bnsum, bnsq);
    bn_finalize<<<1, 256, 0, stream>>>(bnsum, bnsq, gamma, beta, scale, shift);
    bn_apply_elu_bf<<<2048, 256, 0, stream>>>(zdec, scale, shift, zdec_bf);
    wd2_gemm<<<dim3(24, 64), 256, 0, stream>>>(zdec_bf, Wd2t, bd2, out + O_H3);

    // ---- readout + discriminator (split-K=8, bf16 partials)
    readout_mfma2<<<dim3(128, 8), 256, 0, stream>>>(gneigh, HT, vsum_part, rowsum_part);
    readout_disc<<<8192, 128, 0, stream>>>(vsum_part, rowsum_part, h2f, disc_W, disc_b,
                                           out + O_RET, out + O_RETA);
}

// Round 15
// 403.599 us; speedup vs baseline: 1.0009x; 1.0009x over previous
//
#include <hip/hip_runtime.h>
#include <hip/hip_bf16.h>
#include <math.h>

// Problem dims
constexpr int NN  = 8192;
constexpr int EE  = 262144;
constexpr int IN  = 3000;
constexpr int INP = 3008;   // IN padded to mult of 64
constexpr int HID = 256;
constexpr int OUT = 64;

// Output offsets (floats) in d_out: (h2, h3, ret, ret_a, h2, h2_a)
constexpr long O_H2   = 0;
constexpr long O_H3   = 524288;          // 8192*64
constexpr long O_RET  = 25100288;        // + 8192*3000
constexpr long O_RETA = 25116672;        // + 8192*2
constexpr long O_H2B  = 25133056;        // + 8192*2
constexpr long O_H2A  = 25657344;        // + 8192*64

typedef __attribute__((ext_vector_type(8))) short short8v;   // 8 bf16 (4 VGPRs)
typedef __attribute__((ext_vector_type(4))) float f32x4;     // MFMA accumulator

// Compiler-lowered f32->bf16 (RNE). Scalar casts fuse to v_cvt_pk_bf16_f32 [m240].
__device__ __forceinline__ unsigned short f2bf(float f) {
    __hip_bfloat16 h(f);
    unsigned short u;
    __builtin_memcpy(&u, &h, 2);
    return u;
}
__device__ __forceinline__ float bf2f(unsigned short u) {
    return __uint_as_float(((unsigned)u) << 16);
}

// ================= weight transposes (coalesced via LDS tiles) =============================
// W1 [3000][256] f32 -> W1t [256][3008] bf16. grid (47, 4): 64k x 64n tiles.
__global__ __launch_bounds__(256) void cvt_W1t(const float* __restrict__ W,
                                               unsigned short* __restrict__ Wt) {
    __shared__ unsigned short lds[64][68];
    int k0 = blockIdx.x * 64, n0 = blockIdx.y * 64;
    int t = threadIdx.x;
    int rr = t >> 2, c16 = (t & 3) * 16;
    // read W[k0+rr][n0+c16 .. +15] coalesced; store transposed into lds[n][k]
    if (k0 + rr < IN) {
        const float* Wp = W + (long)(k0 + rr) * HID + n0 + c16;
#pragma unroll
        for (int q = 0; q < 16; ++q) lds[c16 + q][rr] = f2bf(Wp[q]);
    } else {
#pragma unroll
        for (int q = 0; q < 16; ++q) lds[c16 + q][rr] = 0;
    }
    __syncthreads();
    // write Wt[n0+rr][k0+c16 .. +15] (32B contiguous per thread)
    unsigned short* Wo = Wt + (long)(n0 + rr) * INP + k0 + c16;
#pragma unroll
    for (int q = 0; q < 16; ++q) Wo[q] = lds[rr][c16 + q];
}

// Wd2 [256][3000] f32 -> Wd2t [3072][256] bf16. grid (48, 4): 64n x 64k tiles.
__global__ __launch_bounds__(256) void cvt_Wd2t(const float* __restrict__ W,
                                                unsigned short* __restrict__ Wt) {
    __shared__ unsigned short lds[64][68];
    int n0 = blockIdx.x * 64, k0 = blockIdx.y * 64;
    int t = threadIdx.x;
    int rr = t >> 2, c16 = (t & 3) * 16;
    // read W[k0+rr][n0+c16 .. +15] coalesced over n; store lds[n][k]
    {
        const float* Wp = W + (long)(k0 + rr) * IN + n0 + c16;
#pragma unroll
        for (int q = 0; q < 16; ++q)
            lds[c16 + q][rr] = (n0 + c16 + q < IN) ? f2bf(Wp[q]) : (unsigned short)0;
    }
    __syncthreads();
    // write Wt[n0+rr][k0+c16 .. +15]
    unsigned short* Wo = Wt + (long)(n0 + rr) * HID + k0 + c16;
#pragma unroll
    for (int q = 0; q < 16; ++q) Wo[q] = lds[rr][c16 + q];
}

// W2 [256][64] -> W2t [64][256] and Wd1 [64][256] -> Wd1t [256][64] in one launch (tiny).
__global__ void cvt_small(const float* __restrict__ W2, unsigned short* __restrict__ W2t,
                          const float* __restrict__ Wd1, unsigned short* __restrict__ Wd1t) {
    int i = blockIdx.x * 256 + threadIdx.x;     // 0..32767
    if (i < 16384) {                            // W2t
        int n = i / HID, k = i % HID;
        W2t[i] = f2bf(W2[(long)k * OUT + n]);
    } else {                                    // Wd1t
        int j = i - 16384;
        int n = j / OUT, k = j % OUT;
        Wd1t[j] = f2bf(Wd1[(long)k * HID + n]);
    }
}

// ================= feat GEMM: [feat;feat_a][16384,3000] @ W1 -> partials ===================
// 128x128 tile, BK=64, reg-prefetch, f32 A converted during staging.
// Split-K=4: partials Cpart[z][16384][256] f32. grid dim3(2,128,4) = 1024 blocks = 4/CU.
__global__ __launch_bounds__(256) void feat_gemm(const float* __restrict__ A0,
                                                 const float* __restrict__ A1,
                                                 const unsigned short* __restrict__ Bt,
                                                 float* __restrict__ Cpart) {
    __shared__ unsigned short As[128][72];
    __shared__ unsigned short Bs[128][72];
    int xb = blockIdx.x, yb = blockIdx.y;
    int pass = yb >> 6;
    int row0 = (yb & 63) * 128, col0 = xb * 128;
    const float* A = pass ? A1 : A0;
    int t = threadIdx.x, w = t >> 6, l = t & 63;
    int sr = t >> 1, sh = (t & 1) * 32;
    int wm = (w >> 1) * 64, wn = (w & 1) * 64;
    int fr = l & 15, fq = l >> 4;
    const unsigned short* Bp = Bt + (long)(col0 + sr) * INP + sh;
    const float* Arow = A + (long)(row0 + sr) * IN;

    int tb = blockIdx.z * 12;
    int ktiles = min(12, 47 - tb);          // 12,12,12,11

    float4  paf[8];
    short8v pb[4];
    auto loadA = [&](int k0) {
        const float* Ar = Arow + k0 + sh;
        if (k0 + 64 <= IN) {
#pragma unroll
            for (int q = 0; q < 8; ++q) paf[q] = *reinterpret_cast<const float4*>(Ar + q * 4);
        } else {
#pragma unroll
            for (int q = 0; q < 8; ++q) {
                int kb = k0 + sh + q * 4;
                float4 v;
                v.x = (kb + 0 < IN) ? Ar[q * 4 + 0] : 0.f;
                v.y = (kb + 1 < IN) ? Ar[q * 4 + 1] : 0.f;
                v.z = (kb + 2 < IN) ? Ar[q * 4 + 2] : 0.f;
                v.w = (kb + 3 < IN) ? Ar[q * 4 + 3] : 0.f;
                paf[q] = v;
            }
        }
    };
    auto loadB = [&](int k0) {
#pragma unroll
        for (int q = 0; q < 4; ++q) pb[q] = *reinterpret_cast<const short8v*>(Bp + k0 + q * 8);
    };
    loadA(tb * 64); loadB(tb * 64);

    f32x4 acc[4][4] = {};
    for (int tt = 0; tt < ktiles; ++tt) {
#pragma unroll
        for (int q = 0; q < 4; ++q) {
            float4 v0 = paf[q * 2], v1 = paf[q * 2 + 1];
            short8v s;
            s[0]=(short)f2bf(v0.x); s[1]=(short)f2bf(v0.y); s[2]=(short)f2bf(v0.z); s[3]=(short)f2bf(v0.w);
            s[4]=(short)f2bf(v1.x); s[5]=(short)f2bf(v1.y); s[6]=(short)f2bf(v1.z); s[7]=(short)f2bf(v1.w);
            *reinterpret_cast<short8v*>(&As[sr][sh + q * 8]) = s;
        }
#pragma unroll
        for (int q = 0; q < 4; ++q)
            *reinterpret_cast<short8v*>(&Bs[sr][sh + q * 8]) = pb[q];
        __syncthreads();
        if (tt + 1 < ktiles) {
            int k0 = (tb + tt + 1) * 64;
            loadA(k0); loadB(k0);
        }
#pragma unroll
        for (int kk = 0; kk < 2; ++kk) {
            short8v fa[4], fb[4];
#pragma unroll
            for (int i = 0; i < 4; ++i)
                fa[i] = *reinterpret_cast<const short8v*>(&As[wm + i * 16 + fr][kk * 32 + fq * 8]);
#pragma unroll
            for (int j = 0; j < 4; ++j)
                fb[j] = *reinterpret_cast<const short8v*>(&Bs[wn + j * 16 + fr][kk * 32 + fq * 8]);
#pragma unroll
            for (int i = 0; i < 4; ++i)
#pragma unroll
                for (int j = 0; j < 4; ++j)
                    acc[i][j] = __builtin_amdgcn_mfma_f32_16x16x32_bf16(fa[i], fb[j], acc[i][j], 0, 0, 0);
        }
        __syncthreads();
    }
    int dc = l & 15;
    long zbase = (long)blockIdx.z * 16384 * 256;
    long rbase = (long)(pass * NN + row0) * 256;
#pragma unroll
    for (int i = 0; i < 4; ++i)
#pragma unroll
        for (int j = 0; j < 4; ++j) {
            int c = col0 + wn + j * 16 + dc;
#pragma unroll
            for (int q = 0; q < 4; ++q) {
                int r = wm + i * 16 + fq * 4 + q;
                Cpart[zbase + rbase + (long)r * 256 + c] = acc[i][j][q];
            }
        }
}

// ---- fused: sum 4 split-K partials -> h_bf2 (bf16) + attention coefficients --------------
__global__ __launch_bounds__(256) void reduce_attn(const float* __restrict__ p,
                                                   const float* __restrict__ att_src,
                                                   const float* __restrict__ att_dst,
                                                   unsigned short* __restrict__ hb,
                                                   float* __restrict__ a_src,
                                                   float* __restrict__ a_dst) {
    int wave = threadIdx.x >> 6, lane = threadIdx.x & 63;
    int n = blockIdx.x * 4 + wave;          // 0..16383
    long base = (long)n * 256 + lane * 4;
    float4 a = *reinterpret_cast<const float4*>(p + base);
    float4 b = *reinterpret_cast<const float4*>(p + 4194304 + base);
    float4 c = *reinterpret_cast<const float4*>(p + 8388608 + base);
    float4 d = *reinterpret_cast<const float4*>(p + 12582912 + base);
    float4 hv;
    hv.x = a.x + b.x + c.x + d.x;
    hv.y = a.y + b.y + c.y + d.y;
    hv.z = a.z + b.z + c.z + d.z;
    hv.w = a.w + b.w + c.w + d.w;
    ushort4 r;
    r.x = f2bf(hv.x); r.y = f2bf(hv.y); r.z = f2bf(hv.z); r.w = f2bf(hv.w);
    *reinterpret_cast<ushort4*>(hb + base) = r;
    float4 vs = *reinterpret_cast<const float4*>(&att_src[lane * 4]);
    float4 vd = *reinterpret_cast<const float4*>(&att_dst[lane * 4]);
    float s1 = hv.x * vs.x + hv.y * vs.y + hv.z * vs.z + hv.w * vs.w;
    float s2 = hv.x * vd.x + hv.y * vd.y + hv.z * vd.z + hv.w * vd.w;
#pragma unroll
    for (int off = 32; off > 0; off >>= 1) {
        s1 += __shfl_down(s1, off);
        s2 += __shfl_down(s2, off);
    }
    if (lane == 0) { a_src[n] = s1; a_dst[n] = s2; }
}

// ================= W2 GEMM with mega-epilogue ==============================================
__global__ __launch_bounds__(256) void w2_gemm(const unsigned short* __restrict__ A,
                                               const unsigned short* __restrict__ Bt,
                                               float* __restrict__ h2f,
                                               unsigned short* __restrict__ h2b,
                                               unsigned short* __restrict__ HT,
                                               float* __restrict__ out) {
    __shared__ unsigned short As[64][72];
    __shared__ unsigned short Bs[64][72];
    int t = threadIdx.x, w = t >> 6, l = t & 63;
    int row0 = blockIdx.y * 64;
    int srow = t >> 2, scol = (t & 3) * 16;
    const unsigned short* Ap = A + (long)(row0 + srow) * HID + scol;
    const unsigned short* Bp = Bt + (long)srow * HID + scol;   // 64 rows only
    int wm = (w >> 1) * 32, wn = (w & 1) * 32;
    int fr = l & 15, fq = l >> 4;

    short8v a0r, a1r, b0r, b1r;
    a0r = *reinterpret_cast<const short8v*>(Ap);
    a1r = *reinterpret_cast<const short8v*>(Ap + 8);
    b0r = *reinterpret_cast<const short8v*>(Bp);
    b1r = *reinterpret_cast<const short8v*>(Bp + 8);

    f32x4 acc[2][2] = {};
    for (int tt = 0; tt < 4; ++tt) {
        *reinterpret_cast<short8v*>(&As[srow][scol])     = a0r;
        *reinterpret_cast<short8v*>(&As[srow][scol + 8]) = a1r;
        *reinterpret_cast<short8v*>(&Bs[srow][scol])     = b0r;
        *reinterpret_cast<short8v*>(&Bs[srow][scol + 8]) = b1r;
        __syncthreads();
        if (tt + 1 < 4) {
            const unsigned short* Ap2 = Ap + (tt + 1) * 64;
            const unsigned short* Bp2 = Bp + (tt + 1) * 64;
            a0r = *reinterpret_cast<const short8v*>(Ap2);
            a1r = *reinterpret_cast<const short8v*>(Ap2 + 8);
            b0r = *reinterpret_cast<const short8v*>(Bp2);
            b1r = *reinterpret_cast<const short8v*>(Bp2 + 8);
        }
#pragma unroll
        for (int kk = 0; kk < 2; ++kk) {
            short8v fa0 = *reinterpret_cast<const short8v*>(&As[wm + fr][kk * 32 + fq * 8]);
            short8v fa1 = *reinterpret_cast<const short8v*>(&As[wm + 16 + fr][kk * 32 + fq * 8]);
            short8v fb0 = *reinterpret_cast<const short8v*>(&Bs[wn + fr][kk * 32 + fq * 8]);
            short8v fb1 = *reinterpret_cast<const short8v*>(&Bs[wn + 16 + fr][kk * 32 + fq * 8]);
            acc[0][0] = __builtin_amdgcn_mfma_f32_16x16x32_bf16(fa0, fb0, acc[0][0], 0, 0, 0);
            acc[0][1] = __builtin_amdgcn_mfma_f32_16x16x32_bf16(fa0, fb1, acc[0][1], 0, 0, 0);
            acc[1][0] = __builtin_amdgcn_mfma_f32_16x16x32_bf16(fa1, fb0, acc[1][0], 0, 0, 0);
            acc[1][1] = __builtin_amdgcn_mfma_f32_16x16x32_bf16(fa1, fb1, acc[1][1], 0, 0, 0);
        }
        __syncthreads();
    }
    int dc = l & 15;
    int pass = row0 >> 13;
#pragma unroll
    for (int i = 0; i < 2; ++i)
#pragma unroll
        for (int j = 0; j < 2; ++j) {
            int c = wn + j * 16 + dc;
#pragma unroll
            for (int q = 0; q < 4; ++q) {
                int r = row0 + wm + i * 16 + fq * 4 + q;
                int n = r & 8191;
                float v = acc[i][j][q];
                unsigned short vb = f2bf(v);
                h2f[(long)pass * 524288 + (long)n * 64 + c] = v;
                if (pass == 0) {
                    out[O_H2  + (long)n * 64 + c] = v;
                    out[O_H2B + (long)n * 64 + c] = v;
                    h2b[(long)n * 64 + c] = vb;
                } else {
                    out[O_H2A + (long)n * 64 + c] = v;
                }
                HT[(long)(pass * 64 + c) * NN + n] = vb;
            }
        }
}

// ================= 128x128 bf16 GEMM (Wd2) ================================================
__global__ __launch_bounds__(256) void wd2_gemm(const unsigned short* __restrict__ A,
                                                const unsigned short* __restrict__ Bt,
                                                const float* __restrict__ bias,
                                                float* __restrict__ Cf) {
    __shared__ unsigned short As[128][72];
    __shared__ unsigned short Bs[128][72];
    int t = threadIdx.x, w = t >> 6, l = t & 63;
    int row0 = blockIdx.y * 128, col0 = blockIdx.x * 128;
    int sr = t >> 1, sh = (t & 1) * 32;
    int wm = (w >> 1) * 64, wn = (w & 1) * 64;
    int fr = l & 15, fq = l >> 4;
    const unsigned short* Ap = A  + (long)(row0 + sr) * HID + sh;
    const unsigned short* Bp = Bt + (long)(col0 + sr) * HID + sh;

    short8v pa[4], pb[4];
#pragma unroll
    for (int q = 0; q < 4; ++q) pa[q] = *reinterpret_cast<const short8v*>(Ap + q * 8);
#pragma unroll
    for (int q = 0; q < 4; ++q) pb[q] = *reinterpret_cast<const short8v*>(Bp + q * 8);

    f32x4 acc[4][4] = {};
    for (int tt = 0; tt < 4; ++tt) {
#pragma unroll
        for (int q = 0; q < 4; ++q) {
            *reinterpret_cast<short8v*>(&As[sr][sh + q * 8]) = pa[q];
            *reinterpret_cast<short8v*>(&Bs[sr][sh + q * 8]) = pb[q];
        }
        __syncthreads();
        if (tt + 1 < 4) {
            int k0 = (tt + 1) * 64;
#pragma unroll
            for (int q = 0; q < 4; ++q) pa[q] = *reinterpret_cast<const short8v*>(Ap + k0 + q * 8);
#pragma unroll
            for (int q = 0; q < 4; ++q) pb[q] = *reinterpret_cast<const short8v*>(Bp + k0 + q * 8);
        }
#pragma unroll
        for (int kk = 0; kk < 2; ++kk) {
            short8v fa[4], fb[4];
#pragma unroll
            for (int i = 0; i < 4; ++i)
                fa[i] = *reinterpret_cast<const short8v*>(&As[wm + i * 16 + fr][kk * 32 + fq * 8]);
#pragma unroll
            for (int j = 0; j < 4; ++j)
                fb[j] = *reinterpret_cast<const short8v*>(&Bs[wn + j * 16 + fr][kk * 32 + fq * 8]);
#pragma unroll
            for (int i = 0; i < 4; ++i)
#pragma unroll
                for (int j = 0; j < 4; ++j)
                    acc[i][j] = __builtin_amdgcn_mfma_f32_16x16x32_bf16(fa[i], fb[j], acc[i][j], 0, 0, 0);
        }
        __syncthreads();
    }
    int dc = l & 15;
#pragma unroll
    for (int i = 0; i < 4; ++i)
#pragma unroll
        for (int j = 0; j < 4; ++j) {
            int c = col0 + wn + j * 16 + dc;
            if (c < IN) {
                float bb = bias[c];
#pragma unroll
                for (int q = 0; q < 4; ++q) {
                    int r = row0 + wm + i * 16 + fq * 4 + q;
                    Cf[(long)r * IN + c] = acc[i][j][q] + bb;
                }
            }
        }
}

// ================= 64x64 bf16 GEMM (Wd1) ===================================================
__global__ __launch_bounds__(256) void wd1_gemm(const unsigned short* __restrict__ A,
                                                const unsigned short* __restrict__ Bt,
                                                const float* __restrict__ bias,
                                                float* __restrict__ C) {
    __shared__ unsigned short As[64][72];
    __shared__ unsigned short Bs[64][72];
    int t = threadIdx.x, w = t >> 6, l = t & 63;
    int row0 = blockIdx.y * 64, col0 = blockIdx.x * 64;
    int srow = t >> 2, scol = (t & 3) * 16;
    const unsigned short* Ap = A  + (long)(row0 + srow) * OUT + scol;   // K=64
    const unsigned short* Bp = Bt + (long)(col0 + srow) * OUT + scol;
    int wm = (w >> 1) * 32, wn = (w & 1) * 32;
    int fr = l & 15, fq = l >> 4;

    *reinterpret_cast<short8v*>(&As[srow][scol])     = *reinterpret_cast<const short8v*>(Ap);
    *reinterpret_cast<short8v*>(&As[srow][scol + 8]) = *reinterpret_cast<const short8v*>(Ap + 8);
    *reinterpret_cast<short8v*>(&Bs[srow][scol])     = *reinterpret_cast<const short8v*>(Bp);
    *reinterpret_cast<short8v*>(&Bs[srow][scol + 8]) = *reinterpret_cast<const short8v*>(Bp + 8);
    __syncthreads();
    f32x4 acc[2][2] = {};
#pragma unroll
    for (int kk = 0; kk < 2; ++kk) {
        short8v fa0 = *reinterpret_cast<const short8v*>(&As[wm + fr][kk * 32 + fq * 8]);
        short8v fa1 = *reinterpret_cast<const short8v*>(&As[wm + 16 + fr][kk * 32 + fq * 8]);
        short8v fb0 = *reinterpret_cast<const short8v*>(&Bs[wn + fr][kk * 32 + fq * 8]);
        short8v fb1 = *reinterpret_cast<const short8v*>(&Bs[wn + 16 + fr][kk * 32 + fq * 8]);
        acc[0][0] = __builtin_amdgcn_mfma_f32_16x16x32_bf16(fa0, fb0, acc[0][0], 0, 0, 0);
        acc[0][1] = __builtin_amdgcn_mfma_f32_16x16x32_bf16(fa0, fb1, acc[0][1], 0, 0, 0);
        acc[1][0] = __builtin_amdgcn_mfma_f32_16x16x32_bf16(fa1, fb0, acc[1][0], 0, 0, 0);
        acc[1][1] = __builtin_amdgcn_mfma_f32_16x16x32_bf16(fa1, fb1, acc[1][1], 0, 0, 0);
    }
    int dc = l & 15;
#pragma unroll
    for (int i = 0; i < 2; ++i)
#pragma unroll
        for (int j = 0; j < 2; ++j) {
            int c = col0 + wn + j * 16 + dc;
            float bb = bias[c];
#pragma unroll
            for (int q = 0; q < 4; ++q) {
                int r = row0 + wm + i * 16 + fq * 4 + q;
                C[(long)r * HID + c] = acc[i][j][q] + bb;
            }
        }
}

// ---------------- readout MFMA: split-K=8, bf16 partials -----------------------------------
__global__ __launch_bounds__(256) void readout_mfma2(const float* __restrict__ gn,
                                                     const unsigned short* __restrict__ HT,
                                                     unsigned short* __restrict__ vsum_part,
                                                     float* __restrict__ rowsum_part) {
    __shared__ unsigned short As[64][72];
    __shared__ unsigned short Bs[128][72];
    __shared__ float rsacc[64][4];
    int t = threadIdx.x, w = t >> 6, l = t & 63;
    int row0 = blockIdx.x * 64;
    int kc = blockIdx.y, kbeg = kc * 1024;
    int asr = t >> 2, asc = (t & 3) * 16;
    int bsr = t >> 1, bsc = (t & 1) * 32;
    const float*          Ap = gn + (long)(row0 + asr) * NN + kbeg + asc;
    const unsigned short* Bp = HT + (long)bsr * NN + kbeg + bsc;
    int wm = (w >> 1) * 32, wn = (w & 1) * 64;
    int fr = l & 15, fq = l >> 4;

    float4  a4[4];
    short8v b8[4];
#pragma unroll
    for (int q = 0; q < 4; ++q) a4[q] = *reinterpret_cast<const float4*>(Ap + q * 4);
#pragma unroll
    for (int q = 0; q < 4; ++q) b8[q] = *reinterpret_cast<const short8v*>(Bp + q * 8);

    f32x4 acc[2][4] = {};
    float myrs = 0.f;
    for (int it = 0; it < 16; ++it) {
#pragma unroll
        for (int q = 0; q < 4; ++q) {
            float4 v = a4[q];
            ushort4 s;
            s.x = f2bf(v.x); s.y = f2bf(v.y); s.z = f2bf(v.z); s.w = f2bf(v.w);
            *reinterpret_cast<ushort4*>(&As[asr][asc + q * 4]) = s;
            myrs += v.x + v.y + v.z + v.w;
        }
#pragma unroll
        for (int q = 0; q < 4; ++q)
            *reinterpret_cast<short8v*>(&Bs[bsr][bsc + q * 8]) = b8[q];
        __syncthreads();
        if (it + 1 < 16) {
            const float*          Ap2 = Ap + (it + 1) * 64;
            const unsigned short* Bp2 = Bp + (it + 1) * 64;
#pragma unroll
            for (int q = 0; q < 4; ++q) a4[q] = *reinterpret_cast<const float4*>(Ap2 + q * 4);
#pragma unroll
            for (int q = 0; q < 4; ++q) b8[q] = *reinterpret_cast<const short8v*>(Bp2 + q * 8);
        }
#pragma unroll
        for (int kk = 0; kk < 2; ++kk) {
            short8v fa0 = *reinterpret_cast<const short8v*>(&As[wm + fr][kk * 32 + fq * 8]);
            short8v fa1 = *reinterpret_cast<const short8v*>(&As[wm + 16 + fr][kk * 32 + fq * 8]);
#pragma unroll
            for (int j = 0; j < 4; ++j) {
                short8v fb = *reinterpret_cast<const short8v*>(&Bs[wn + j * 16 + fr][kk * 32 + fq * 8]);
                acc[0][j] = __builtin_amdgcn_mfma_f32_16x16x32_bf16(fa0, fb, acc[0][j], 0, 0, 0);
                acc[1][j] = __builtin_amdgcn_mfma_f32_16x16x32_bf16(fa1, fb, acc[1][j], 0, 0, 0);
            }
        }
        __syncthreads();
    }
    rsacc[asr][t & 3] = myrs;
    __syncthreads();
    if (t < 64)
        rowsum_part[(long)kc * NN + row0 + t] =
            rsacc[t][0] + rsacc[t][1] + rsacc[t][2] + rsacc[t][3];
    int dc = l & 15;
#pragma unroll
    for (int i = 0; i < 2; ++i)
#pragma unroll
        for (int j = 0; j < 4; ++j) {
            int c = wn + j * 16 + dc;
#pragma unroll
            for (int q = 0; q < 4; ++q) {
                int r = row0 + wm + i * 16 + fq * 4 + q;
                vsum_part[((long)kc * NN + r) * 128 + c] = f2bf(acc[i][j][q]);
            }
        }
}

// ---------------- CSR build ----------------------------------------------------------------
__global__ void deg_count(const int* __restrict__ dst, int* __restrict__ deg) {
    int i = blockIdx.x * 256 + threadIdx.x;
    if (i < EE) atomicAdd(&deg[dst[i]], 1);
}

__global__ __launch_bounds__(256) void scan_offsets(const int* __restrict__ deg,
                                                    int* __restrict__ off,
                                                    int* __restrict__ cursor) {
    __shared__ int part[256];
    int t = threadIdx.x;
    int base = t * 32;
    int local[32];
    int s = 0;
#pragma unroll
    for (int i = 0; i < 32; ++i) { local[i] = s; s += deg[base + i]; }
    part[t] = s;
    __syncthreads();
    for (int o2 = 1; o2 < 256; o2 <<= 1) {
        int v = (t >= o2) ? part[t - o2] : 0;
        __syncthreads();
        part[t] += v;
        __syncthreads();
    }
    int pre = (t == 0) ? 0 : part[t - 1];
#pragma unroll
    for (int i = 0; i < 32; ++i) {
        int v = pre + local[i];
        off[base + i] = v;
        cursor[base + i] = v;
    }
}

__global__ void scatter_edges(const int* __restrict__ src, const int* __restrict__ dst,
                              int* __restrict__ cursor, int* __restrict__ ssrc) {
    int i = blockIdx.x * 256 + threadIdx.x;
    if (i >= EE) return;
    int slot = atomicAdd(&cursor[dst[i]], 1);
    ssrc[slot] = src[i];
}

// ---------------- fused GAT gather (batched both passes) -----------------------------------
__global__ __launch_bounds__(256) void gat_gather(const int* __restrict__ ssrc,
                                                  const int* __restrict__ off,
                                                  const int* __restrict__ deg,
                                                  const float* __restrict__ asrc2,
                                                  const float* __restrict__ adst2,
                                                  const unsigned short* __restrict__ hb2,
                                                  unsigned short* __restrict__ gat2) {
    int wv = threadIdx.x >> 6, lane = threadIdx.x & 63;
    int d = blockIdx.x * 4 + wv;        // 0..16383
    int pass = d >> 13, node = d & 8191;
    const float* asrc = asrc2 + pass * NN;
    const unsigned short* h = hb2 + (long)pass * NN * HID;
    int o = off[node], n = deg[node];
    float ad = adst2[d];

    float m = -INFINITY;
    for (int j = lane; j < n; j += 64) {
        float e = asrc[ssrc[o + j]] + ad;
        e = e > 0.f ? e : 0.2f * e;
        m = fmaxf(m, e);
    }
#pragma unroll
    for (int t = 32; t; t >>= 1) m = fmaxf(m, __shfl_xor(m, t));
    float z = 0.f;
    for (int j = lane; j < n; j += 64) {
        float e = asrc[ssrc[o + j]] + ad;
        e = e > 0.f ? e : 0.2f * e;
        z += expf(e - m);
    }
#pragma unroll
    for (int t = 32; t; t >>= 1) z += __shfl_xor(z, t);
    float zinv = 1.0f / (z + 1e-16f);

    float4 acc = {0.f, 0.f, 0.f, 0.f};
    int j = 0;
    for (; j + 2 <= n; j += 2) {
        int s0 = ssrc[o + j], s1 = ssrc[o + j + 1];
        const ushort4 h0 = *reinterpret_cast<const ushort4*>(&h[(long)s0 * HID + lane * 4]);
        const ushort4 h1 = *reinterpret_cast<const ushort4*>(&h[(long)s1 * HID + lane * 4]);
        float e0 = asrc[s0] + ad; e0 = e0 > 0.f ? e0 : 0.2f * e0;
        float e1 = asrc[s1] + ad; e1 = e1 > 0.f ? e1 : 0.2f * e1;
        float a0 = expf(e0 - m) * zinv;
        float a1 = expf(e1 - m) * zinv;
        acc.x += a0 * bf2f(h0.x) + a1 * bf2f(h1.x);
        acc.y += a0 * bf2f(h0.y) + a1 * bf2f(h1.y);
        acc.z += a0 * bf2f(h0.z) + a1 * bf2f(h1.z);
        acc.w += a0 * bf2f(h0.w) + a1 * bf2f(h1.w);
    }
    if (j < n) {
        int s0 = ssrc[o + j];
        const ushort4 h0 = *reinterpret_cast<const ushort4*>(&h[(long)s0 * HID + lane * 4]);
        float e0 = asrc[s0] + ad; e0 = e0 > 0.f ? e0 : 0.2f * e0;
        float a0 = expf(e0 - m) * zinv;
        acc.x += a0 * bf2f(h0.x); acc.y += a0 * bf2f(h0.y);
        acc.z += a0 * bf2f(h0.z); acc.w += a0 * bf2f(h0.w);
    }
    ushort4 r;
    r.x = f2bf(acc.x > 0.f ? acc.x : expm1f(acc.x));
    r.y = f2bf(acc.y > 0.f ? acc.y : expm1f(acc.y));
    r.z = f2bf(acc.z > 0.f ? acc.z : expm1f(acc.z));
    r.w = f2bf(acc.w > 0.f ? acc.w : expm1f(acc.w));
    *reinterpret_cast<ushort4*>(&gat2[(long)d * HID + lane * 4]) = r;
}

// ---------------- batchnorm ----------------------------------------------------------------
__global__ void bn_partial(const float* __restrict__ zd, float* __restrict__ s,
                           float* __restrict__ sq) {
    int t = threadIdx.x;
    float a = 0.f, b = 0.f;
    int r0 = blockIdx.x * 32;
    for (int r = r0; r < r0 + 32; ++r) {
        float v = zd[(long)r * HID + t];
        a += v;
        b += v * v;
    }
    atomicAdd(&s[t], a);
    atomicAdd(&sq[t], b);
}

__global__ void bn_finalize(const float* __restrict__ s, const float* __restrict__ sq,
                            const float* __restrict__ gamma, const float* __restrict__ beta,
                            float* __restrict__ scale, float* __restrict__ shift) {
    int t = threadIdx.x;
    float mean = s[t] / (float)NN;
    float var  = sq[t] / (float)NN - mean * mean;
    float sc   = gamma[t] * rsqrtf(var + 1e-5f);
    scale[t] = sc;
    shift[t] = beta[t] - mean * sc;
}

__global__ void bn_apply_elu_bf(const float* __restrict__ zd, const float* __restrict__ scale,
                                const float* __restrict__ shift, unsigned short* __restrict__ zb) {
    for (long i = (long)blockIdx.x * blockDim.x + threadIdx.x; i < (long)NN * HID;
         i += (long)gridDim.x * blockDim.x) {
        int c = (int)(i & 255);
        float v = zd[i] * scale[c] + shift[c];
        v = v > 0.f ? v : expm1f(v);
        zb[i] = f2bf(v);
    }
}

// ---------------- fused readout-norm + discriminator ---------------------------------------
__global__ void readout_disc(const unsigned short* __restrict__ vsum_part,
                             const float* __restrict__ rowsum_part,
                             const float* __restrict__ h2f,
                             const float* __restrict__ W, const float* __restrict__ b,
                             float* __restrict__ ret, float* __restrict__ reta) {
    __shared__ float gg[128];
    int r = blockIdx.x, t = threadIdx.x;
    float rs = 0.f, v = 0.f;
#pragma unroll
    for (int kc = 0; kc < 8; ++kc) {
        rs += rowsum_part[(long)kc * NN + r];
        v  += bf2f(vsum_part[((long)kc * NN + r) * 128 + t]);
    }
    v /= rs;
    int w = t >> 6, lane = t & 63;
    float sq = v * v;
#pragma unroll
    for (int off = 32; off > 0; off >>= 1) sq += __shfl_xor(sq, off);
    float nrm = fmaxf(sqrtf(sq), 1e-12f);
    gg[t] = 1.0f / (1.0f + expf(-(v / nrm)));
    __syncthreads();
    const float* hp_base = h2f + (w ? 524288 : 0);
    const float* hm_base = h2f + (w ? 0 : 524288);
    float u = 0.f;
#pragma unroll 8
    for (int e = 0; e < 64; ++e) u += W[lane * 64 + e] * gg[w * 64 + e];
    float hp = hp_base[(long)r * 64 + lane];
    float hm = hm_base[(long)r * 64 + lane];
    float t1 = hp * u, t2 = hm * u;
#pragma unroll
    for (int off = 32; off > 0; off >>= 1) {
        t1 += __shfl_xor(t1, off);
        t2 += __shfl_xor(t2, off);
    }
    if (lane == 0) {
        float bb = b[0];
        float* dstp = w ? reta : ret;
        dstp[r * 2]     = t1 + bb;
        dstp[r * 2 + 1] = t2 + bb;
    }
}

// ---------------- driver -------------------------------------------------------------------
extern "C" void kernel_launch(void* const* d_in, const int* in_sizes, int n_in,
                              void* d_out, int out_size, void* d_ws, size_t ws_size,
                              hipStream_t stream) {
    const float* feat    = (const float*)d_in[0];
    const float* feat_a  = (const float*)d_in[1];
    const float* gneigh  = (const float*)d_in[2];
    const float* W1      = (const float*)d_in[3];
    const float* att_src = (const float*)d_in[4];
    const float* att_dst = (const float*)d_in[5];
    const float* W2      = (const float*)d_in[6];
    const float* Wd1     = (const float*)d_in[7];
    const float* bd1     = (const float*)d_in[8];
    const float* gamma   = (const float*)d_in[9];
    const float* beta    = (const float*)d_in[10];
    const float* Wd2     = (const float*)d_in[11];
    const float* bd2     = (const float*)d_in[12];
    const float* disc_W  = (const float*)d_in[13];
    const float* disc_b  = (const float*)d_in[14];
    const int*   eidx    = (const int*)d_in[15];
    const int*   src = eidx;
    const int*   dst = eidx + EE;
    float* out = (float*)d_out;

    // workspace layout (floats)
    float* w = (float*)d_ws;
    unsigned short* h_bf2  = (unsigned short*)w;                   // [2][8192][256] bf16 = 2097152 f
    unsigned short* gat_bf2 = (unsigned short*)(w + 2097152);      // [2][8192][256] bf16 = 2097152 f
    float* zdec    = w + 4194304;                                  // [8192][256] f32 = 2097152 f
    unsigned short* zdec_bf = (unsigned short*)(zdec + 2097152);   // 1048576 f
    float* h2f     = zdec + 2097152 + 1048576;                     // [2][8192][64] = 1048576 f
    unsigned short* h2b = (unsigned short*)(h2f + 1048576);        // [8192][64] bf16 = 262144 f
    unsigned short* HT  = h2b + 524288;                            // [128][8192] bf16 = 524288 f
    float* asrc2   = (float*)(HT + 1048576);                       // 16384
    float* adst2   = asrc2 + 16384;                                // 16384
    float* bnsum   = adst2 + 16384;           // 256
    float* bnsq    = bnsum + 256;             // 256
    float* scale   = bnsq + 256;              // 256
    float* shift   = scale + 256;             // 256
    unsigned short* W1t  = (unsigned short*)(shift + 256);         // 770048 sh
    unsigned short* W2t  = W1t + 770048;                           // 16384 sh
    unsigned short* Wd1t = W2t + 16384;                            // 16384 sh
    unsigned short* Wd2t = Wd1t + 16384;                           // 786432 sh
    int*   ideg    = (int*)(Wd2t + 786432);   // 8192
    int*   ioff    = ideg + 8192;             // 8192
    int*   icur    = ioff + 8192;             // 8192
    int*   issrc   = icur + 8192;             // 262144
    // feat split-K partials: 4 x [16384][256] f32 = 64 MB in the not-yet-written h3 region
    float* part = out + O_H3;                 // 16777216 f <= 24576000 f available
    // readout-phase reuse: vsum bf16 8x[8192][128] in h_bf2+gat_bf2; rowsum f32 in zdec
    unsigned short* vsum_part = (unsigned short*)w;
    float* rowsum_part = zdec;

    // ---- one-time weight conversions (coalesced LDS-tiled transposes)
    cvt_W1t<<<dim3(47, 4), 256, 0, stream>>>(W1, W1t);
    cvt_Wd2t<<<dim3(48, 4), 256, 0, stream>>>(Wd2, Wd2t);
    cvt_small<<<128, 256, 0, stream>>>(W2, W2t, Wd1, Wd1t);

    // ---- CSR build
    hipMemsetAsync(ideg, 0, 8192 * 4, stream);
    deg_count<<<EE / 256, 256, 0, stream>>>(dst, ideg);
    scan_offsets<<<1, 256, 0, stream>>>(ideg, ioff, icur);
    scatter_edges<<<EE / 256, 256, 0, stream>>>(src, dst, icur, issrc);

    // ---- encoder (both passes batched; split-K=4 for occupancy)
    feat_gemm<<<dim3(2, 128, 4), 256, 0, stream>>>(feat, feat_a, W1t, part);
    reduce_attn<<<4096, 256, 0, stream>>>(part, att_src, att_dst, h_bf2, asrc2, adst2);
    gat_gather<<<4096, 256, 0, stream>>>(issrc, ioff, ideg, asrc2, adst2, h_bf2, gat_bf2);
    w2_gemm<<<dim3(1, 256), 256, 0, stream>>>(gat_bf2, W2t, h2f, h2b, HT, out);

    // ---- decoder: h3 = elu(BN(h2 @ Wd1 + bd1)) @ Wd2 + bd2
    wd1_gemm<<<dim3(4, 128), 256, 0, stream>>>(h2b, Wd1t, bd1, zdec);
    hipMemsetAsync(bnsum, 0, 512 * 4, stream);
    bn_partial<<<256, 256, 0, stream>>>(zdec, bnsum, bnsq);
    bn_finalize<<<1, 256, 0, stream>>>(bnsum, bnsq, gamma, beta, scale, shift);
    bn_apply_elu_bf<<<2048, 256, 0, stream>>>(zdec, scale, shift, zdec_bf);
    wd2_gemm<<<dim3(24, 64), 256, 0, stream>>>(zdec_bf, Wd2t, bd2, out + O_H3);

    // ---- readout + discriminator (split-K=8, bf16 partials)
    readout_mfma2<<<dim3(128, 8), 256, 0, stream>>>(gneigh, HT, vsum_part, rowsum_part);
    readout_disc<<<8192, 128, 0, stream>>>(vsum_part, rowsum_part, h2f, disc_W, disc_b,
                                           out + O_RET, out + O_RETA);
}